// Round 15
// baseline (714.659 us; speedup 1.0000x reference)
//
#include <hip/hip_runtime.h>
#include <math.h>

#define N_U 100000
#define N_V 100000
#define D 128
#define E1 3200000
#define E2 3200000
#define ETOT (E1 + E2)

#define NBUCK 196      // buckets of 512 dst nodes: dst >> 9
#define SLACK 35000    // per-bucket record capacity (expected 32768 +/- ~180)
#define PCHUNK 4096    // edges per partition block
#define CSTRIDE 32     // bucketCursor padding: one counter per 128B cache line

#define NBL_V 1563     // linear blocks for x_v (ceil(100000/64))
#define NBL_U 1563     // linear blocks for x_u
#define NBL_P 1563     // partition blocks (ceil(6400000/4096))

typedef __bf16 bf16x8 __attribute__((ext_vector_type(8)));
typedef float f32x4 __attribute__((ext_vector_type(4)));

__device__ __forceinline__ unsigned short f2b(float f) {
  union { float f; unsigned int u; } v; v.f = f;
  unsigned int u = v.u;
  unsigned int r = u + 0x7fffu + ((u >> 16) & 1u);
  return (unsigned short)(r >> 16);
}
__device__ __forceinline__ float b2f(unsigned short s) {
  union { unsigned int u; float f; } v; v.u = ((unsigned int)s) << 16; return v.f;
}
__device__ __forceinline__ float b2f_lo(unsigned w) {
  union { unsigned u; float f; } v; v.u = w << 16; return v.f;
}
__device__ __forceinline__ float b2f_hi(unsigned w) {
  union { unsigned u; float f; } v; v.u = w & 0xffff0000u; return v.f;
}

// ---------------------------------------------------------------------------
// Stage 0: all weight converts fused. MFMA-fragment-packed bf16 layout:
// frag = (n>>4)*KG + (k>>5); idx = frag*512 + ((n&15)+16*((k>>3)&3))*8 + (k&7)
// ---------------------------------------------------------------------------
__global__ __launch_bounds__(256) void convert_all(
    const float* __restrict__ W_r1, const float* __restrict__ W_r2,
    const float* __restrict__ W_gate, const float* __restrict__ W_aggr,
    unsigned short* __restrict__ Wr1F, unsigned short* __restrict__ Wr2F,
    unsigned short* __restrict__ WgF, unsigned short* __restrict__ WaF) {
  const int b = blockIdx.x;
  if (b < 128) {
    const float* W = (b < 64) ? W_r1 : W_r2;
    unsigned short* WF = (b < 64) ? Wr1F : Wr2F;
    int idx = (b & 63) * 256 + threadIdx.x;
    int k = idx >> 7, n = idx & 127;
    int f = (n >> 4) * 4 + (k >> 5);
    int out = f * 512 + ((n & 15) + 16 * ((k >> 3) & 3)) * 8 + (k & 7);
    WF[out] = f2b(W[k * 128 + n]);
  } else if (b < 704) {
    int idx = (b - 128) * 256 + threadIdx.x;
    int k = idx / 384, n = idx - k * 384;
    int f = (n >> 4) * 12 + (k >> 5);
    int out = f * 512 + ((n & 15) + 16 * ((k >> 3) & 3)) * 8 + (k & 7);
    WgF[out] = f2b(W_gate[k * 384 + n]);
  } else {
    int idx = (b - 704) * 256 + threadIdx.x;
    int k = idx >> 7, n = idx & 127;
    int f = (n >> 4) * 12 + (k >> 5);
    int out = f * 512 + ((n & 15) + 16 * ((k >> 3) & 3)) * 8 + (k & 7);
    WaF[out] = f2b(W_aggr[k * 128 + n]);
  }
}

// ---------------------------------------------------------------------------
// Stage 1: partition + linear_v + linear_u fused. Packed 4B records,
// coalesced Hb stores through LDS, padded bucketCursor.
// ---------------------------------------------------------------------------
#define LM 64
union SMem1 {
  struct { unsigned short Xs[LM][136]; } lin;                       // 17408 B
  struct {
    int hist[256]; int scan_s[256]; int lstart[256];
    int gbase[NBUCK]; int lcur[NBUCK];
    uint2 buf[PCHUNK];                                              // 32 KB
  } part;                                                           // ~37.4 KB
};

__device__ __forceinline__ void do_linear(
    const float* __restrict__ X, const unsigned short* __restrict__ WF,
    unsigned short* __restrict__ Hb, int nrows, int bid, SMem1& sm) {
  const int t = threadIdx.x;
  const int row0 = bid * LM;

  for (int i = t * 4; i < LM * 128; i += 1024) {
    int n = i >> 7, j = i & 127;
    int r = row0 + n;
    float4 v = make_float4(0.f, 0.f, 0.f, 0.f);
    if (r < nrows) v = *(const float4*)&X[(size_t)r * 128 + j];
    unsigned long long w =
        (unsigned long long)f2b(v.x) |
        ((unsigned long long)f2b(v.y) << 16) |
        ((unsigned long long)f2b(v.z) << 32) |
        ((unsigned long long)f2b(v.w) << 48);
    *(unsigned long long*)&sm.lin.Xs[n][j] = w;
  }
  __syncthreads();

  const int wv = t >> 6;
  const int ln = t & 63;
  const int lr = ln & 15;
  const int lq = ln >> 4;
  const int m0 = wv * 16;

  bf16x8 a[4];
#pragma unroll
  for (int ks = 0; ks < 4; ks++)
    a[ks] = *(const bf16x8*)&sm.lin.Xs[m0 + lr][ks * 32 + lq * 8];
  __syncthreads();  // all fragment loads done before Xs is reused for output

#pragma unroll
  for (int np = 0; np < 4; np++) {
    const int n0 = np * 32;
    f32x4 acc0 = {0.f, 0.f, 0.f, 0.f};
    f32x4 acc1 = {0.f, 0.f, 0.f, 0.f};
    const unsigned short* B0 = WF + (size_t)(np * 2) * 4 * 512 + ln * 8;
    const unsigned short* B1 = B0 + 4 * 512;
#pragma unroll
    for (int ks = 0; ks < 4; ks++) {
      bf16x8 b0 = *(const bf16x8*)(B0 + ks * 512);
      bf16x8 b1 = *(const bf16x8*)(B1 + ks * 512);
      acc0 = __builtin_amdgcn_mfma_f32_16x16x32_bf16(a[ks], b0, acc0, 0, 0, 0);
      acc1 = __builtin_amdgcn_mfma_f32_16x16x32_bf16(a[ks], b1, acc1, 0, 0, 0);
    }
#pragma unroll
    for (int r = 0; r < 4; r++) {
      int row = m0 + lq * 4 + r;
      sm.lin.Xs[row][n0 + lr] = f2b(acc0[r]);
      sm.lin.Xs[row][n0 + 16 + lr] = f2b(acc1[r]);
    }
  }
  __syncthreads();

  // coalesced copy-out: thread t -> row t>>2, 64B part t&3 (full 128B lines)
  {
    int row = t >> 2, part = t & 3;
    int grow = row0 + row;
    if (grow < nrows) {
      uint4* dst = (uint4*)&Hb[(size_t)grow * 128 + part * 32];
      const unsigned short* src = &sm.lin.Xs[row][part * 32];
      uint4 w0 = *(const uint4*)(src);
      uint4 w1 = *(const uint4*)(src + 8);
      uint4 w2 = *(const uint4*)(src + 16);
      uint4 w3 = *(const uint4*)(src + 24);
      dst[0] = w0; dst[1] = w1; dst[2] = w2; dst[3] = w3;
    }
  }
}

// Records packed to 4B: (enc<<9)|(dst&511) — 18+9=27 bits.
__device__ __forceinline__ void do_partition(
    const int* __restrict__ e1, const int* __restrict__ e2,
    int* __restrict__ bucketCursor, unsigned* __restrict__ recs,
    int bid, SMem1& sm) {
  const int t = threadIdx.x;
  const long base = (long)bid * PCHUNK;
  const int n = (int)min((long)PCHUNK, (long)ETOT - base);

  sm.part.hist[t] = 0;
  __syncthreads();

  uint2 myrec[PCHUNK / 256];
  int myb[PCHUNK / 256];
#pragma unroll
  for (int k = 0; k < PCHUNK / 256; k++) {
    int idx = t + k * 256;
    int enc = 0, dst = 0;
    if (idx < n) {
      long i = base + idx;
      if (i < E1) {
        dst = e1[E1 + i];
        enc = N_V + e1[i];
      } else {
        long j = i - E1;
        dst = e2[E2 + j];
        enc = e2[j];
      }
      atomicAdd(&sm.part.hist[dst >> 9], 1);
    }
    myrec[k] = make_uint2(((unsigned)enc << 9) | ((unsigned)dst & 511u),
                          (unsigned)(dst >> 9));  // static index k
    myb[k] = dst >> 9;
  }
  __syncthreads();

  int v = sm.part.hist[t];
  sm.part.scan_s[t] = v;
  __syncthreads();
  for (int off = 1; off < 256; off <<= 1) {
    int tmp = (t >= off) ? sm.part.scan_s[t - off] : 0;
    __syncthreads();
    sm.part.scan_s[t] += tmp;
    __syncthreads();
  }
  sm.part.lstart[t] = sm.part.scan_s[t] - v;
  if (t < NBUCK) {
    sm.part.gbase[t] = atomicAdd(&bucketCursor[t * CSTRIDE], v);
    sm.part.lcur[t] = sm.part.scan_s[t] - v;
  }
  __syncthreads();

#pragma unroll
  for (int k = 0; k < PCHUNK / 256; k++) {
    int idx = t + k * 256;
    if (idx < n) {
      int p = atomicAdd(&sm.part.lcur[myb[k]], 1);
      sm.part.buf[p] = myrec[k];
    }
  }
  __syncthreads();

  for (int p = t; p < n; p += 256) {
    uint2 r = sm.part.buf[p];
    int b = (int)r.y;
    recs[(size_t)b * SLACK + sm.part.gbase[b] + (p - sm.part.lstart[b])] = r.x;
  }
}

__global__ __launch_bounds__(256) void stage1(
    const float* __restrict__ x_v, const float* __restrict__ x_u,
    const unsigned short* __restrict__ Wr2F, const unsigned short* __restrict__ Wr1F,
    unsigned short* __restrict__ Hb,
    const int* __restrict__ e1, const int* __restrict__ e2,
    int* __restrict__ bucketCursor, unsigned* __restrict__ recs) {
  __shared__ SMem1 sm;
  const int b = blockIdx.x;
  if (b < NBL_P) {
    do_partition(e1, e2, bucketCursor, recs, b, sm);
  } else if (b < NBL_P + NBL_V) {
    do_linear(x_v, Wr2F, Hb, N_V, b - NBL_P, sm);
  } else {
    do_linear(x_u, Wr1F, Hb + (size_t)N_V * D, N_U, b - NBL_P - NBL_V, sm);
  }
}

// ---------------------------------------------------------------------------
// Stage 2: bucket_fill, 1024 threads/block, packed 4B records.
// ---------------------------------------------------------------------------
__global__ __launch_bounds__(1024) void bucket_fill(
    const unsigned* __restrict__ recs, const int* __restrict__ bucketCnt,
    int* __restrict__ row_ptr, int* __restrict__ col) {
  __shared__ int hist[512];
  __shared__ int s[512];
  __shared__ int curF[512];
  __shared__ int curB[512];
  __shared__ int sh_outBase;
  const int t = threadIdx.x;
  const int b = blockIdx.x;
  const size_t slack = (size_t)b * SLACK;
  const int n = bucketCnt[b * CSTRIDE];

  // scan of the 196 bucket counts (first 256 threads) -> outBase
  int cv = 0;
  if (t < 256) {
    cv = (t < NBUCK) ? bucketCnt[t * CSTRIDE] : 0;
    s[t] = cv;
  }
  __syncthreads();
  for (int off = 1; off < 256; off <<= 1) {
    int tmp = 0;
    if (t < 256 && t >= off) tmp = s[t - off];
    __syncthreads();
    if (t < 256) s[t] += tmp;
    __syncthreads();
  }
  if (t == b) sh_outBase = s[t] - cv;
  __syncthreads();
  const int outBase = sh_outBase;

  if (t < 512) hist[t] = 0;
  __syncthreads();
  for (int p = t; p < n; p += 1024)
    atomicAdd(&hist[recs[slack + p] & 511u], 1);
  __syncthreads();

  int v = 0;
  if (t < 512) {
    v = hist[t];
    s[t] = v;
  }
  __syncthreads();
  for (int off = 1; off < 512; off <<= 1) {
    int tmp = 0;
    if (t < 512 && t >= off) tmp = s[t - off];
    __syncthreads();
    if (t < 512) s[t] += tmp;
    __syncthreads();
  }
  if (t < 512) {
    int excl = s[t] - v;
    curF[t] = excl;       // front cursor: r2 edges (enc < N_V)
    curB[t] = excl + v;   // back cursor: r1 edges (enc >= N_V)
    int nd = (b << 9) + t;
    if (nd < N_V) row_ptr[nd] = outBase + excl;
  }
  if (b == 0 && t == 0) row_ptr[N_V] = ETOT;
  __syncthreads();

  for (int p = t; p < n; p += 1024) {
    unsigned r = recs[slack + p];
    int local = (int)(r & 511u);
    unsigned enc = r >> 9;
    int q;
    if (enc >= (unsigned)N_V) q = atomicSub(&curB[local], 1) - 1;
    else q = atomicAdd(&curF[local], 1);
    col[outBase + q] = (int)(enc << 8);  // byte offset of Hb row
  }
}

// ---------------------------------------------------------------------------
// Fused aggregate + epilogue v2, EM=32. r14's EM=64 version regressed because
// LDS 50.7KB capped occupancy at 12 waves/CU and the latency-bound gather
// rate fell 3.65->1.9 TB/s. EM=32 halves LDS (~25.3KB) -> 6 blocks/CU =
// 24 waves/CU, restoring standalone-aggregate occupancy while keeping the
// fusion's traffic saving (no SumB/MxB round trip) and block-level overlap
// of gather (memory) and GEMM (MFMA) phases. Arithmetic identical to r14
// (which passed absmax 0.125); only geometry halves.
// ---------------------------------------------------------------------------
#define AGG1(w)                                        \
  do {                                                 \
    float lo = b2f_lo(w), hi = b2f_hi(w);              \
    s[2 * q] += lo; s[2 * q + 1] += hi;                \
    m[2 * q] = fmaxf(m[2 * q], lo);                    \
    m[2 * q + 1] = fmaxf(m[2 * q + 1], hi);            \
  } while (0)

#define EM 32
__global__ __launch_bounds__(256, 6) void agg_epilogue(
    const unsigned short* __restrict__ Hb, const int* __restrict__ row_ptr,
    const int* __restrict__ col, const unsigned short* __restrict__ WgF,
    const float* __restrict__ bg, const unsigned short* __restrict__ WaF,
    const float* __restrict__ ba, float* __restrict__ Out) {
  __shared__ unsigned short Ts[EM][392];   // 25088 B
  __shared__ float invs[EM];
  __shared__ int cnts[EM];

  const int t = threadIdx.x;
  const int node0 = blockIdx.x * EM;

  if (t < EM) {
    int nd = node0 + t;
    int c = 0;
    if (nd < N_V) c = row_ptr[nd + 1] - row_ptr[nd];
    cnts[t] = c;
    invs[t] = 1.0f / (float)(c > 0 ? c : 1);
  }
  __syncthreads();

  const int wv = t >> 6;
  const int lane = t & 63;
  const int grp = lane >> 4;   // which edge within group-of-4
  const int fl = lane & 15;    // feat slot: feats 8*fl .. 8*fl+7
  const char* Hc = (const char*)Hb;
  const int byteoff = fl * 16;

  // ---- Phase A: wave wv aggregates nodes [wv*8, wv*8+8) ----
  for (int i = 0; i < 8; i++) {
    const int n = (wv << 3) + i;
    const int node = node0 + n;
    int start = 0, end = 0;
    if (node < N_V) { start = row_ptr[node]; end = row_ptr[node + 1]; }

    float s[8] = {0.f, 0.f, 0.f, 0.f, 0.f, 0.f, 0.f, 0.f};
    float m[8] = {0.f, 0.f, 0.f, 0.f, 0.f, 0.f, 0.f, 0.f};

    int e0 = start;
    for (; e0 + 31 < end; e0 += 32) {
      uint4 v[8];
#pragma unroll
      for (int g = 0; g < 8; g++) {
        int e = e0 + g * 4 + grp;
        v[g] = *(const uint4*)(Hc + (unsigned)col[e] + byteoff);
      }
#pragma unroll
      for (int g = 0; g < 8; g++) {
        { int q = 0; AGG1(v[g].x); }
        { int q = 1; AGG1(v[g].y); }
        { int q = 2; AGG1(v[g].z); }
        { int q = 3; AGG1(v[g].w); }
      }
    }
    for (; e0 < end; e0 += 4) {
      int e = e0 + grp;
      int ec = e < end ? e : (end - 1);
      uint4 v = *(const uint4*)(Hc + (unsigned)col[ec] + byteoff);
      if (e >= end) { v.x = 0u; v.y = 0u; v.z = 0u; v.w = 0u; }
      { int q = 0; AGG1(v.x); }
      { int q = 1; AGG1(v.y); }
      { int q = 2; AGG1(v.z); }
      { int q = 3; AGG1(v.w); }
    }

    // reduce across the 4 edge-groups (lanes l, l^16, l^32, l^48)
#pragma unroll
    for (int k = 0; k < 8; k++) {
      s[k] += __shfl_xor(s[k], 16, 64);
      m[k] = fmaxf(m[k], __shfl_xor(m[k], 16, 64));
      s[k] += __shfl_xor(s[k], 32, 64);
      m[k] = fmaxf(m[k], __shfl_xor(m[k], 32, 64));
    }

    if (lane < 16) {
      uint4 o;
      o.x = (unsigned)f2b(s[0]) | ((unsigned)f2b(s[1]) << 16);
      o.y = (unsigned)f2b(s[2]) | ((unsigned)f2b(s[3]) << 16);
      o.z = (unsigned)f2b(s[4]) | ((unsigned)f2b(s[5]) << 16);
      o.w = (unsigned)f2b(s[6]) | ((unsigned)f2b(s[7]) << 16);
      *(uint4*)&Ts[n][fl * 8] = o;
      // mean from the bf16-ROUNDED sum (bit-identical to old Ts build)
      float inv = invs[n];
      uint4 om;
      om.x = (unsigned)f2b(b2f((unsigned short)o.x) * inv) |
             ((unsigned)f2b(b2f((unsigned short)(o.x >> 16)) * inv) << 16);
      om.y = (unsigned)f2b(b2f((unsigned short)o.y) * inv) |
             ((unsigned)f2b(b2f((unsigned short)(o.y >> 16)) * inv) << 16);
      om.z = (unsigned)f2b(b2f((unsigned short)o.z) * inv) |
             ((unsigned)f2b(b2f((unsigned short)(o.z >> 16)) * inv) << 16);
      om.w = (unsigned)f2b(b2f((unsigned short)o.w) * inv) |
             ((unsigned)f2b(b2f((unsigned short)(o.w >> 16)) * inv) << 16);
      *(uint4*)&Ts[n][128 + fl * 8] = om;
    } else if (lane < 32) {
      uint4 o;
      o.x = (unsigned)f2b(m[0]) | ((unsigned)f2b(m[1]) << 16);
      o.y = (unsigned)f2b(m[2]) | ((unsigned)f2b(m[3]) << 16);
      o.z = (unsigned)f2b(m[4]) | ((unsigned)f2b(m[5]) << 16);
      o.w = (unsigned)f2b(m[6]) | ((unsigned)f2b(m[7]) << 16);
      *(uint4*)&Ts[n][256 + fl * 8] = o;
    }
  }
  __syncthreads();

  // ---- Phase B: gate GEMM -> gate apply -> aggr GEMM (rows 0..31) ----
  const int ln = lane;
  const int lr = ln & 15;
  const int lq = ln >> 4;

  f32x4 acc[2][6];
#pragma unroll
  for (int m2 = 0; m2 < 2; m2++)
#pragma unroll
    for (int nt = 0; nt < 6; nt++) acc[m2][nt] = (f32x4){0.f, 0.f, 0.f, 0.f};

  const unsigned short* Bg = WgF + (size_t)(wv * 6) * 12 * 512 + ln * 8;

#pragma unroll 2
  for (int kc = 0; kc < 12; kc++) {
    bf16x8 b[6];
#pragma unroll
    for (int nt = 0; nt < 6; nt++)
      b[nt] = *(const bf16x8*)(Bg + (nt * 12 + kc) * 512);
    bf16x8 a[2];
#pragma unroll
    for (int m2 = 0; m2 < 2; m2++)
      a[m2] = *(const bf16x8*)&Ts[m2 * 16 + lr][kc * 32 + lq * 8];
#pragma unroll
    for (int m2 = 0; m2 < 2; m2++)
#pragma unroll
      for (int nt = 0; nt < 6; nt++)
        acc[m2][nt] = __builtin_amdgcn_mfma_f32_16x16x32_bf16(a[m2], b[nt], acc[m2][nt], 0, 0, 0);
  }
  __syncthreads();  // all Ts reads done before gated rewrite

  // Gate apply: wave wv owns cols [wv*96, wv*96+96), all 32 rows.
#pragma unroll
  for (int nt = 0; nt < 6; nt++) {
    int cg = wv * 96 + nt * 16 + lr;
    float bgv = bg[cg];
#pragma unroll
    for (int m2 = 0; m2 < 2; m2++) {
#pragma unroll
      for (int r = 0; r < 4; r++) {
        int row = m2 * 16 + lq * 4 + r;
        float g = 1.f / (1.f + __expf(-(acc[m2][nt][r] + bgv)));
        Ts[row][cg] = f2b(b2f(Ts[row][cg]) * g);
      }
    }
  }
  __syncthreads();  // gated Ts ready for aggr GEMM

  f32x4 acc2[2][2];
#pragma unroll
  for (int m2 = 0; m2 < 2; m2++)
#pragma unroll
    for (int nt = 0; nt < 2; nt++) acc2[m2][nt] = (f32x4){0.f, 0.f, 0.f, 0.f};

  const unsigned short* Ba = WaF + (size_t)(wv * 2) * 12 * 512 + ln * 8;

#pragma unroll 2
  for (int kc = 0; kc < 12; kc++) {
    bf16x8 b[2];
#pragma unroll
    for (int nt = 0; nt < 2; nt++)
      b[nt] = *(const bf16x8*)(Ba + (nt * 12 + kc) * 512);
    bf16x8 a[2];
#pragma unroll
    for (int m2 = 0; m2 < 2; m2++)
      a[m2] = *(const bf16x8*)&Ts[m2 * 16 + lr][kc * 32 + lq * 8];
#pragma unroll
    for (int m2 = 0; m2 < 2; m2++)
#pragma unroll
      for (int nt = 0; nt < 2; nt++)
        acc2[m2][nt] = __builtin_amdgcn_mfma_f32_16x16x32_bf16(a[m2], b[nt], acc2[m2][nt], 0, 0, 0);
  }

#pragma unroll
  for (int nt = 0; nt < 2; nt++) {
    int cg = wv * 32 + nt * 16 + lr;
    float bav = ba[cg];
#pragma unroll
    for (int m2 = 0; m2 < 2; m2++) {
#pragma unroll
      for (int r = 0; r < 4; r++) {
        int row = m2 * 16 + lq * 4 + r;
        int nd = node0 + row;
        if (nd < N_V) {
          float msk = (cnts[row] > 0) ? 1.f : 0.f;
          Out[(size_t)nd * D + cg] = (acc2[m2][nt][r] + bav) * msk;
        }
      }
    }
  }
}

// ---------------------------------------------------------------------------
extern "C" void kernel_launch(void* const* d_in, const int* in_sizes, int n_in,
                              void* d_out, int out_size, void* d_ws, size_t ws_size,
                              hipStream_t stream) {
  const float* x_u = (const float*)d_in[0];
  const float* x_v = (const float*)d_in[1];
  const float* W_r1 = (const float*)d_in[2];
  const float* W_r2 = (const float*)d_in[3];
  const float* W_gate = (const float*)d_in[4];
  const float* b_gate = (const float*)d_in[5];
  const float* W_aggr = (const float*)d_in[6];
  const float* b_aggr = (const float*)d_in[7];
  const int* e1 = (const int*)d_in[8];
  const int* e2 = (const int*)d_in[9];
  float* out = (float*)d_out;

  char* ws = (char*)d_ws;
  size_t off = 0;
  unsigned short* Hb = (unsigned short*)(ws + off); off += (size_t)(N_V + N_U) * D * 2;
  int* colA = (int*)(ws + off);        off += (size_t)ETOT * 4;
  unsigned* recs = (unsigned*)(ws + off); off += (size_t)NBUCK * SLACK * 4;
  int* row_ptr = (int*)(ws + off);     off += (size_t)(N_V + 1) * 4;
  int* bucketCursor = (int*)(ws + off); off += (size_t)NBUCK * CSTRIDE * 4;
  unsigned short* Wg16 = (unsigned short*)(ws + off); off += (size_t)384 * 384 * 2;
  unsigned short* Wa16 = (unsigned short*)(ws + off); off += (size_t)128 * 384 * 2;
  unsigned short* Wr1T = (unsigned short*)(ws + off); off += (size_t)128 * 128 * 2;
  unsigned short* Wr2T = (unsigned short*)(ws + off); off += (size_t)128 * 128 * 2;

  hipMemsetAsync(bucketCursor, 0, (size_t)NBUCK * CSTRIDE * 4, stream);

  convert_all<<<896, 256, 0, stream>>>(W_r1, W_r2, W_gate, W_aggr,
                                       Wr1T, Wr2T, Wg16, Wa16);

  stage1<<<NBL_P + NBL_V + NBL_U, 256, 0, stream>>>(
      x_v, x_u, Wr2T, Wr1T, Hb, e1, e2, bucketCursor, recs);

  bucket_fill<<<NBUCK, 1024, 0, stream>>>(recs, bucketCursor, row_ptr, colA);

  agg_epilogue<<<(N_V + EM - 1) / EM, 256, 0, stream>>>(
      Hb, row_ptr, colA, Wg16, b_gate, Wa16, b_aggr, out);
}

// Round 16
// 573.071 us; speedup vs baseline: 1.2471x; 1.2471x over previous
//
#include <hip/hip_runtime.h>
#include <math.h>

#define N_U 100000
#define N_V 100000
#define D 128
#define E1 3200000
#define E2 3200000
#define ETOT (E1 + E2)

#define NBUCK 196      // buckets of 512 dst nodes: dst >> 9
#define SLACK 35000    // per-bucket record capacity (expected 32768 +/- ~180)
#define PCHUNK 4096    // edges per partition block
#define CSTRIDE 32     // bucketCursor padding: one counter per 128B cache line

#define NBL_V 1563     // linear blocks for x_v (ceil(100000/64))
#define NBL_U 1563     // linear blocks for x_u
#define NBL_P 1563     // partition blocks (ceil(6400000/4096))

typedef __bf16 bf16x8 __attribute__((ext_vector_type(8)));
typedef float f32x4 __attribute__((ext_vector_type(4)));

__device__ __forceinline__ unsigned short f2b(float f) {
  union { float f; unsigned int u; } v; v.f = f;
  unsigned int u = v.u;
  unsigned int r = u + 0x7fffu + ((u >> 16) & 1u);
  return (unsigned short)(r >> 16);
}
__device__ __forceinline__ float b2f(unsigned short s) {
  union { unsigned int u; float f; } v; v.u = ((unsigned int)s) << 16; return v.f;
}
__device__ __forceinline__ float b2f_lo(unsigned w) {
  union { unsigned u; float f; } v; v.u = w << 16; return v.f;
}
__device__ __forceinline__ float b2f_hi(unsigned w) {
  union { unsigned u; float f; } v; v.u = w & 0xffff0000u; return v.f;
}

// ---------------------------------------------------------------------------
// Stage 0: all weight converts fused (+ bucketCursor zeroing folded in: the
// first 25 blocks clear the 196*32 padded ints; convert_all completes before
// stage1 reads the cursors). MFMA-fragment-packed bf16 layout:
// frag = (n>>4)*KG + (k>>5); idx = frag*512 + ((n&15)+16*((k>>3)&3))*8 + (k&7)
// ---------------------------------------------------------------------------
__global__ __launch_bounds__(256) void convert_all(
    const float* __restrict__ W_r1, const float* __restrict__ W_r2,
    const float* __restrict__ W_gate, const float* __restrict__ W_aggr,
    unsigned short* __restrict__ Wr1F, unsigned short* __restrict__ Wr2F,
    unsigned short* __restrict__ WgF, unsigned short* __restrict__ WaF,
    int* __restrict__ bucketCursor) {
  const int b = blockIdx.x;
  {
    int gid = b * 256 + threadIdx.x;
    if (gid < NBUCK * CSTRIDE) bucketCursor[gid] = 0;
  }
  if (b < 128) {
    const float* W = (b < 64) ? W_r1 : W_r2;
    unsigned short* WF = (b < 64) ? Wr1F : Wr2F;
    int idx = (b & 63) * 256 + threadIdx.x;
    int k = idx >> 7, n = idx & 127;
    int f = (n >> 4) * 4 + (k >> 5);
    int out = f * 512 + ((n & 15) + 16 * ((k >> 3) & 3)) * 8 + (k & 7);
    WF[out] = f2b(W[k * 128 + n]);
  } else if (b < 704) {
    int idx = (b - 128) * 256 + threadIdx.x;
    int k = idx / 384, n = idx - k * 384;
    int f = (n >> 4) * 12 + (k >> 5);
    int out = f * 512 + ((n & 15) + 16 * ((k >> 3) & 3)) * 8 + (k & 7);
    WgF[out] = f2b(W_gate[k * 384 + n]);
  } else {
    int idx = (b - 704) * 256 + threadIdx.x;
    int k = idx >> 7, n = idx & 127;
    int f = (n >> 4) * 12 + (k >> 5);
    int out = f * 512 + ((n & 15) + 16 * ((k >> 3) & 3)) * 8 + (k & 7);
    WaF[out] = f2b(W_aggr[k * 128 + n]);
  }
}

// ---------------------------------------------------------------------------
// Stage 1: partition + linear_v + linear_u fused (partition blocks FIRST so
// the heavy scatter work starts immediately and overlaps the linear wave).
// Packed 4B records, coalesced Hb stores through LDS, padded bucketCursor.
// ---------------------------------------------------------------------------
#define LM 64
union SMem1 {
  struct { unsigned short Xs[LM][136]; } lin;                       // 17408 B
  struct {
    int hist[256]; int scan_s[256]; int lstart[256];
    int gbase[NBUCK]; int lcur[NBUCK];
    uint2 buf[PCHUNK];                                              // 32 KB
  } part;                                                           // ~37.4 KB
};

__device__ __forceinline__ void do_linear(
    const float* __restrict__ X, const unsigned short* __restrict__ WF,
    unsigned short* __restrict__ Hb, int nrows, int bid, SMem1& sm) {
  const int t = threadIdx.x;
  const int row0 = bid * LM;

  for (int i = t * 4; i < LM * 128; i += 1024) {
    int n = i >> 7, j = i & 127;
    int r = row0 + n;
    float4 v = make_float4(0.f, 0.f, 0.f, 0.f);
    if (r < nrows) v = *(const float4*)&X[(size_t)r * 128 + j];
    unsigned long long w =
        (unsigned long long)f2b(v.x) |
        ((unsigned long long)f2b(v.y) << 16) |
        ((unsigned long long)f2b(v.z) << 32) |
        ((unsigned long long)f2b(v.w) << 48);
    *(unsigned long long*)&sm.lin.Xs[n][j] = w;
  }
  __syncthreads();

  const int wv = t >> 6;
  const int ln = t & 63;
  const int lr = ln & 15;
  const int lq = ln >> 4;
  const int m0 = wv * 16;

  bf16x8 a[4];
#pragma unroll
  for (int ks = 0; ks < 4; ks++)
    a[ks] = *(const bf16x8*)&sm.lin.Xs[m0 + lr][ks * 32 + lq * 8];
  __syncthreads();  // all fragment loads done before Xs is reused for output

#pragma unroll
  for (int np = 0; np < 4; np++) {
    const int n0 = np * 32;
    f32x4 acc0 = {0.f, 0.f, 0.f, 0.f};
    f32x4 acc1 = {0.f, 0.f, 0.f, 0.f};
    const unsigned short* B0 = WF + (size_t)(np * 2) * 4 * 512 + ln * 8;
    const unsigned short* B1 = B0 + 4 * 512;
#pragma unroll
    for (int ks = 0; ks < 4; ks++) {
      bf16x8 b0 = *(const bf16x8*)(B0 + ks * 512);
      bf16x8 b1 = *(const bf16x8*)(B1 + ks * 512);
      acc0 = __builtin_amdgcn_mfma_f32_16x16x32_bf16(a[ks], b0, acc0, 0, 0, 0);
      acc1 = __builtin_amdgcn_mfma_f32_16x16x32_bf16(a[ks], b1, acc1, 0, 0, 0);
    }
#pragma unroll
    for (int r = 0; r < 4; r++) {
      int row = m0 + lq * 4 + r;
      sm.lin.Xs[row][n0 + lr] = f2b(acc0[r]);
      sm.lin.Xs[row][n0 + 16 + lr] = f2b(acc1[r]);
    }
  }
  __syncthreads();

  // coalesced copy-out: thread t -> row t>>2, 64B part t&3 (full 128B lines)
  {
    int row = t >> 2, part = t & 3;
    int grow = row0 + row;
    if (grow < nrows) {
      uint4* dst = (uint4*)&Hb[(size_t)grow * 128 + part * 32];
      const unsigned short* src = &sm.lin.Xs[row][part * 32];
      uint4 w0 = *(const uint4*)(src);
      uint4 w1 = *(const uint4*)(src + 8);
      uint4 w2 = *(const uint4*)(src + 16);
      uint4 w3 = *(const uint4*)(src + 24);
      dst[0] = w0; dst[1] = w1; dst[2] = w2; dst[3] = w3;
    }
  }
}

// Records packed to 4B: (enc<<9)|(dst&511) — 18+9=27 bits.
__device__ __forceinline__ void do_partition(
    const int* __restrict__ e1, const int* __restrict__ e2,
    int* __restrict__ bucketCursor, unsigned* __restrict__ recs,
    int bid, SMem1& sm) {
  const int t = threadIdx.x;
  const long base = (long)bid * PCHUNK;
  const int n = (int)min((long)PCHUNK, (long)ETOT - base);

  sm.part.hist[t] = 0;
  __syncthreads();

  uint2 myrec[PCHUNK / 256];
  int myb[PCHUNK / 256];
#pragma unroll
  for (int k = 0; k < PCHUNK / 256; k++) {
    int idx = t + k * 256;
    int enc = 0, dst = 0;
    if (idx < n) {
      long i = base + idx;
      if (i < E1) {
        dst = e1[E1 + i];
        enc = N_V + e1[i];
      } else {
        long j = i - E1;
        dst = e2[E2 + j];
        enc = e2[j];
      }
      atomicAdd(&sm.part.hist[dst >> 9], 1);
    }
    myrec[k] = make_uint2(((unsigned)enc << 9) | ((unsigned)dst & 511u),
                          (unsigned)(dst >> 9));  // static index k
    myb[k] = dst >> 9;
  }
  __syncthreads();

  int v = sm.part.hist[t];
  sm.part.scan_s[t] = v;
  __syncthreads();
  for (int off = 1; off < 256; off <<= 1) {
    int tmp = (t >= off) ? sm.part.scan_s[t - off] : 0;
    __syncthreads();
    sm.part.scan_s[t] += tmp;
    __syncthreads();
  }
  sm.part.lstart[t] = sm.part.scan_s[t] - v;
  if (t < NBUCK) {
    sm.part.gbase[t] = atomicAdd(&bucketCursor[t * CSTRIDE], v);
    sm.part.lcur[t] = sm.part.scan_s[t] - v;
  }
  __syncthreads();

#pragma unroll
  for (int k = 0; k < PCHUNK / 256; k++) {
    int idx = t + k * 256;
    if (idx < n) {
      int p = atomicAdd(&sm.part.lcur[myb[k]], 1);
      sm.part.buf[p] = myrec[k];
    }
  }
  __syncthreads();

  for (int p = t; p < n; p += 256) {
    uint2 r = sm.part.buf[p];
    int b = (int)r.y;
    recs[(size_t)b * SLACK + sm.part.gbase[b] + (p - sm.part.lstart[b])] = r.x;
  }
}

__global__ __launch_bounds__(256) void stage1(
    const float* __restrict__ x_v, const float* __restrict__ x_u,
    const unsigned short* __restrict__ Wr2F, const unsigned short* __restrict__ Wr1F,
    unsigned short* __restrict__ Hb,
    const int* __restrict__ e1, const int* __restrict__ e2,
    int* __restrict__ bucketCursor, unsigned* __restrict__ recs) {
  __shared__ SMem1 sm;
  const int b = blockIdx.x;
  if (b < NBL_P) {
    do_partition(e1, e2, bucketCursor, recs, b, sm);
  } else if (b < NBL_P + NBL_V) {
    do_linear(x_v, Wr2F, Hb, N_V, b - NBL_P, sm);
  } else {
    do_linear(x_u, Wr1F, Hb + (size_t)N_V * D, N_U, b - NBL_P - NBL_V, sm);
  }
}

// ---------------------------------------------------------------------------
// Stage 2: bucket_fill, 1024 threads/block, packed 4B records. Integrated
// bucket-base scan (padded bucketCursor). Two-ended fill:
// each node's segment is [r2 edges ... r1 edges].
// col holds BYTE offsets into Hb (enc*256).
// ---------------------------------------------------------------------------
__global__ __launch_bounds__(1024) void bucket_fill(
    const unsigned* __restrict__ recs, const int* __restrict__ bucketCnt,
    int* __restrict__ row_ptr, int* __restrict__ col) {
  __shared__ int hist[512];
  __shared__ int s[512];
  __shared__ int curF[512];
  __shared__ int curB[512];
  __shared__ int sh_outBase;
  const int t = threadIdx.x;
  const int b = blockIdx.x;
  const size_t slack = (size_t)b * SLACK;
  const int n = bucketCnt[b * CSTRIDE];

  // scan of the 196 bucket counts (first 256 threads) -> outBase
  int cv = 0;
  if (t < 256) {
    cv = (t < NBUCK) ? bucketCnt[t * CSTRIDE] : 0;
    s[t] = cv;
  }
  __syncthreads();
  for (int off = 1; off < 256; off <<= 1) {
    int tmp = 0;
    if (t < 256 && t >= off) tmp = s[t - off];
    __syncthreads();
    if (t < 256) s[t] += tmp;
    __syncthreads();
  }
  if (t == b) sh_outBase = s[t] - cv;
  __syncthreads();
  const int outBase = sh_outBase;

  if (t < 512) hist[t] = 0;
  __syncthreads();
  for (int p = t; p < n; p += 1024)
    atomicAdd(&hist[recs[slack + p] & 511u], 1);
  __syncthreads();

  int v = 0;
  if (t < 512) {
    v = hist[t];
    s[t] = v;
  }
  __syncthreads();
  for (int off = 1; off < 512; off <<= 1) {
    int tmp = 0;
    if (t < 512 && t >= off) tmp = s[t - off];
    __syncthreads();
    if (t < 512) s[t] += tmp;
    __syncthreads();
  }
  if (t < 512) {
    int excl = s[t] - v;
    curF[t] = excl;       // front cursor: r2 edges (enc < N_V)
    curB[t] = excl + v;   // back cursor: r1 edges (enc >= N_V)
    int nd = (b << 9) + t;
    if (nd < N_V) row_ptr[nd] = outBase + excl;
  }
  if (b == 0 && t == 0) row_ptr[N_V] = ETOT;
  __syncthreads();

  for (int p = t; p < n; p += 1024) {
    unsigned r = recs[slack + p];
    int local = (int)(r & 511u);
    unsigned enc = r >> 9;
    int q;
    if (enc >= (unsigned)N_V) q = atomicSub(&curB[local], 1) - 1;
    else q = atomicAdd(&curF[local], 1);
    col[outBase + q] = (int)(enc << 8);  // byte offset of Hb row
  }
}

// ---------------------------------------------------------------------------
// Aggregation (proven round-6 inner loop), two half-node dispatches.
// One wave per dst node, 4 edges per wave-instruction, uint4 full-row reads,
// butterfly shfl reduce.
// ---------------------------------------------------------------------------
#define AGG1(w)                                        \
  do {                                                 \
    float lo = b2f_lo(w), hi = b2f_hi(w);              \
    s[2 * q] += lo; s[2 * q + 1] += hi;                \
    m[2 * q] = fmaxf(m[2 * q], lo);                    \
    m[2 * q + 1] = fmaxf(m[2 * q + 1], hi);            \
  } while (0)

__global__ __launch_bounds__(256) void aggregate_kernel(
    const unsigned short* __restrict__ Hb, const int* __restrict__ row_ptr,
    const int* __restrict__ col, unsigned int* __restrict__ SumB,
    unsigned int* __restrict__ MxB, int nodeBase) {
  const int node = nodeBase + blockIdx.x * 4 + (threadIdx.x >> 6);
  const int lane = threadIdx.x & 63;
  const int grp = lane >> 4;   // which edge within group-of-4
  const int fl = lane & 15;    // feat slot: feats 8*fl .. 8*fl+7
  const int start = row_ptr[node];
  const int end = row_ptr[node + 1];
  const char* Hc = (const char*)Hb;
  const int byteoff = fl * 16;

  float s[8] = {0.f, 0.f, 0.f, 0.f, 0.f, 0.f, 0.f, 0.f};
  float m[8] = {0.f, 0.f, 0.f, 0.f, 0.f, 0.f, 0.f, 0.f};

  int i = start;
  for (; i + 31 < end; i += 32) {
    uint4 v[8];
#pragma unroll
    for (int g = 0; g < 8; g++) {
      int e = i + g * 4 + grp;
      v[g] = *(const uint4*)(Hc + (unsigned)col[e] + byteoff);
    }
#pragma unroll
    for (int g = 0; g < 8; g++) {
      { int q = 0; AGG1(v[g].x); }
      { int q = 1; AGG1(v[g].y); }
      { int q = 2; AGG1(v[g].z); }
      { int q = 3; AGG1(v[g].w); }
    }
  }
  for (; i < end; i += 4) {
    int e = i + grp;
    int ec = e < end ? e : (end - 1);
    uint4 v = *(const uint4*)(Hc + (unsigned)col[ec] + byteoff);
    if (e >= end) { v.x = 0u; v.y = 0u; v.z = 0u; v.w = 0u; }
    { int q = 0; AGG1(v.x); }
    { int q = 1; AGG1(v.y); }
    { int q = 2; AGG1(v.z); }
    { int q = 3; AGG1(v.w); }
  }

  // reduce across the 4 edge-groups (lanes l, l^16, l^32, l^48)
#pragma unroll
  for (int k = 0; k < 8; k++) {
    s[k] += __shfl_xor(s[k], 16, 64);
    m[k] = fmaxf(m[k], __shfl_xor(m[k], 16, 64));
    s[k] += __shfl_xor(s[k], 32, 64);
    m[k] = fmaxf(m[k], __shfl_xor(m[k], 32, 64));
  }

  if (lane < 16) {
    uint4 o;
    o.x = (unsigned)f2b(s[0]) | ((unsigned)f2b(s[1]) << 16);
    o.y = (unsigned)f2b(s[2]) | ((unsigned)f2b(s[3]) << 16);
    o.z = (unsigned)f2b(s[4]) | ((unsigned)f2b(s[5]) << 16);
    o.w = (unsigned)f2b(s[6]) | ((unsigned)f2b(s[7]) << 16);
    ((uint4*)SumB)[(size_t)node * 16 + fl] = o;
  } else if (lane < 32) {
    uint4 o;
    o.x = (unsigned)f2b(m[0]) | ((unsigned)f2b(m[1]) << 16);
    o.y = (unsigned)f2b(m[2]) | ((unsigned)f2b(m[3]) << 16);
    o.z = (unsigned)f2b(m[4]) | ((unsigned)f2b(m[5]) << 16);
    o.w = (unsigned)f2b(m[6]) | ((unsigned)f2b(m[7]) << 16);
    ((uint4*)MxB)[(size_t)node * 16 + fl] = o;
  }
}

// ---------------------------------------------------------------------------
// MFMA epilogue: B-fragments from fragment-packed weight tables -> every wave
// B-load is one coalesced 1KB burst. Barrier-free k-loops, wave M-blocking.
// ---------------------------------------------------------------------------
#define EM 64
__global__ __launch_bounds__(256, 3) void epilogue_mfma(
    const unsigned short* __restrict__ SumB, const unsigned short* __restrict__ MxB,
    const int* __restrict__ row_ptr, const unsigned short* __restrict__ WgF,
    const float* __restrict__ bg, const unsigned short* __restrict__ WaF,
    const float* __restrict__ ba, float* __restrict__ Out) {
  __shared__ unsigned short Ts[EM][392];   // 50176 B
  __shared__ float invs[EM];
  __shared__ int cnts[EM];

  const int t = threadIdx.x;
  const int node0 = blockIdx.x * EM;

  if (t < EM) {
    int nd = node0 + t;
    int c = 0;
    if (nd < N_V) c = row_ptr[nd + 1] - row_ptr[nd];
    cnts[t] = c;
    invs[t] = 1.0f / (float)(c > 0 ? c : 1);
  }
  __syncthreads();

  // Build Ts = [sum(128) | mean(128) | max(128)] bf16, 16B-vectorized.
  {
    const uint4* Sv = (const uint4*)SumB;
    const uint4* Mv = (const uint4*)MxB;
    for (int i = t; i < EM * 16; i += 256) {
      int n = i >> 4, u = i & 15;
      int nd = node0 + n;
      uint4 s = make_uint4(0u, 0u, 0u, 0u);
      uint4 m4 = make_uint4(0u, 0u, 0u, 0u);
      if (nd < N_V) {
        s = Sv[(size_t)nd * 16 + u];
        m4 = Mv[(size_t)nd * 16 + u];
      }
      float inv = invs[n];
      *(uint4*)&Ts[n][u * 8] = s;
      unsigned sw[4] = {s.x, s.y, s.z, s.w};
      unsigned mr[4];
#pragma unroll
      for (int q = 0; q < 4; q++) {
        unsigned short lo = f2b(b2f((unsigned short)sw[q]) * inv);
        unsigned short hi = f2b(b2f((unsigned short)(sw[q] >> 16)) * inv);
        mr[q] = (unsigned)lo | ((unsigned)hi << 16);
      }
      *(uint4*)&Ts[n][128 + u * 8] = make_uint4(mr[0], mr[1], mr[2], mr[3]);
      *(uint4*)&Ts[n][256 + u * 8] = m4;
    }
  }
  __syncthreads();

  const int wv = t >> 6;
  const int ln = t & 63;
  const int lr = ln & 15;
  const int lq = ln >> 4;

  // ---- Gate GEMM: acc[m][nt], rows m*16+lq*4+r, cols wv*96+nt*16+lr ----
  f32x4 acc[4][6];
#pragma unroll
  for (int m = 0; m < 4; m++)
#pragma unroll
    for (int nt = 0; nt < 6; nt++) acc[m][nt] = (f32x4){0.f, 0.f, 0.f, 0.f};

  const unsigned short* Bg = WgF + (size_t)(wv * 6) * 12 * 512 + ln * 8;

#pragma unroll 2
  for (int kc = 0; kc < 12; kc++) {
    bf16x8 b[6];
#pragma unroll
    for (int nt = 0; nt < 6; nt++)
      b[nt] = *(const bf16x8*)(Bg + (nt * 12 + kc) * 512);
    bf16x8 a[4];
#pragma unroll
    for (int m = 0; m < 4; m++)
      a[m] = *(const bf16x8*)&Ts[m * 16 + lr][kc * 32 + lq * 8];
#pragma unroll
    for (int m = 0; m < 4; m++)
#pragma unroll
      for (int nt = 0; nt < 6; nt++)
        acc[m][nt] = __builtin_amdgcn_mfma_f32_16x16x32_bf16(a[m], b[nt], acc[m][nt], 0, 0, 0);
  }
  __syncthreads();  // all Ts reads done before gated rewrite

  // Gate apply: wave wv owns cols [wv*96, wv*96+96), all 64 rows.
#pragma unroll
  for (int nt = 0; nt < 6; nt++) {
    int cg = wv * 96 + nt * 16 + lr;
    float bgv = bg[cg];
#pragma unroll
    for (int m = 0; m < 4; m++) {
#pragma unroll
      for (int r = 0; r < 4; r++) {
        int row = m * 16 + lq * 4 + r;
        float g = 1.f / (1.f + __expf(-(acc[m][nt][r] + bgv)));
        Ts[row][cg] = f2b(b2f(Ts[row][cg]) * g);
      }
    }
  }
  __syncthreads();  // gated Ts ready for aggr GEMM

  // ---- Aggr GEMM: acc2[m][nt], cols wv*32+nt*16+lr ----
  f32x4 acc2[4][2];
#pragma unroll
  for (int m = 0; m < 4; m++)
#pragma unroll
    for (int nt = 0; nt < 2; nt++) acc2[m][nt] = (f32x4){0.f, 0.f, 0.f, 0.f};

  const unsigned short* Ba = WaF + (size_t)(wv * 2) * 12 * 512 + ln * 8;

#pragma unroll 2
  for (int kc = 0; kc < 12; kc++) {
    bf16x8 b[2];
#pragma unroll
    for (int nt = 0; nt < 2; nt++)
      b[nt] = *(const bf16x8*)(Ba + (nt * 12 + kc) * 512);
    bf16x8 a[4];
#pragma unroll
    for (int m = 0; m < 4; m++)
      a[m] = *(const bf16x8*)&Ts[m * 16 + lr][kc * 32 + lq * 8];
#pragma unroll
    for (int m = 0; m < 4; m++)
#pragma unroll
      for (int nt = 0; nt < 2; nt++)
        acc2[m][nt] = __builtin_amdgcn_mfma_f32_16x16x32_bf16(a[m], b[nt], acc2[m][nt], 0, 0, 0);
  }

#pragma unroll
  for (int nt = 0; nt < 2; nt++) {
    int cg = wv * 32 + nt * 16 + lr;
    float bav = ba[cg];
#pragma unroll
    for (int m = 0; m < 4; m++) {
#pragma unroll
      for (int r = 0; r < 4; r++) {
        int row = m * 16 + lq * 4 + r;
        int nd = node0 + row;
        if (nd < N_V) {
          float msk = (cnts[row] > 0) ? 1.f : 0.f;
          Out[(size_t)nd * D + cg] = (acc2[m][nt][r] + bav) * msk;
        }
      }
    }
  }
}

// ---------------------------------------------------------------------------
extern "C" void kernel_launch(void* const* d_in, const int* in_sizes, int n_in,
                              void* d_out, int out_size, void* d_ws, size_t ws_size,
                              hipStream_t stream) {
  const float* x_u = (const float*)d_in[0];
  const float* x_v = (const float*)d_in[1];
  const float* W_r1 = (const float*)d_in[2];
  const float* W_r2 = (const float*)d_in[3];
  const float* W_gate = (const float*)d_in[4];
  const float* b_gate = (const float*)d_in[5];
  const float* W_aggr = (const float*)d_in[6];
  const float* b_aggr = (const float*)d_in[7];
  const int* e1 = (const int*)d_in[8];
  const int* e2 = (const int*)d_in[9];
  float* out = (float*)d_out;

  char* ws = (char*)d_ws;
  size_t off = 0;
  unsigned short* Hb = (unsigned short*)(ws + off); off += (size_t)(N_V + N_U) * D * 2;
  unsigned int* SumB = (unsigned int*)(ws + off);   off += (size_t)N_V * D * 2;
  unsigned int* MxB = (unsigned int*)(ws + off);    off += (size_t)N_V * D * 2;
  int* colA = (int*)(ws + off);        off += (size_t)ETOT * 4;
  unsigned* recs = (unsigned*)(ws + off); off += (size_t)NBUCK * SLACK * 4;
  int* row_ptr = (int*)(ws + off);     off += (size_t)(N_V + 1) * 4;
  int* bucketCursor = (int*)(ws + off); off += (size_t)NBUCK * CSTRIDE * 4;
  unsigned short* Wg16 = (unsigned short*)(ws + off); off += (size_t)384 * 384 * 2;
  unsigned short* Wa16 = (unsigned short*)(ws + off); off += (size_t)128 * 384 * 2;
  unsigned short* Wr1T = (unsigned short*)(ws + off); off += (size_t)128 * 128 * 2;
  unsigned short* Wr2T = (unsigned short*)(ws + off); off += (size_t)128 * 128 * 2;

  convert_all<<<896, 256, 0, stream>>>(W_r1, W_r2, W_gate, W_aggr,
                                       Wr1T, Wr2T, Wg16, Wa16, bucketCursor);

  stage1<<<NBL_P + NBL_V + NBL_U, 256, 0, stream>>>(
      x_v, x_u, Wr2T, Wr1T, Hb, e1, e2, bucketCursor, recs);

  bucket_fill<<<NBUCK, 1024, 0, stream>>>(recs, bucketCursor, row_ptr, colA);

  aggregate_kernel<<<N_V / 8, 256, 0, stream>>>(Hb, row_ptr, colA, SumB, MxB, 0);
  aggregate_kernel<<<N_V / 8, 256, 0, stream>>>(Hb, row_ptr, colA, SumB, MxB, N_V / 2);

  epilogue_mfma<<<(N_V + EM - 1) / EM, 256, 0, stream>>>(
      (const unsigned short*)SumB, (const unsigned short*)MxB, row_ptr,
      Wg16, b_gate, Wa16, b_aggr, out);
}